// Round 1
// 206.746 us; speedup vs baseline: 1.3816x; 1.3816x over previous
//
#include <hip/hip_runtime.h>
#include <math.h>

#define N 4096
#define DIN 512
#define D 32
#define JC 8

// ---------------- encoder: x[4096,512] -> latent[4096,32] + normed rows, fused ----------------
__global__ __launch_bounds__(256) void enc_kernel(
    const float* __restrict__ x,
    const float* __restrict__ w1, const float* __restrict__ b1,
    const float* __restrict__ w2, const float* __restrict__ b2,
    const float* __restrict__ w3, const float* __restrict__ b3,
    float* __restrict__ latent, float* __restrict__ normed) {
  __shared__ float xs[16][512];
  __shared__ float h1s[16][128];
  __shared__ float h2s[16][64];
  const int t = threadIdx.x;
  const int r0 = blockIdx.x * 16;

  const float4* xg = (const float4*)(x + (size_t)r0 * DIN);
  float4* xl = (float4*)&xs[0][0];
#pragma unroll
  for (int i = 0; i < 8; ++i) xl[t + i * 256] = xg[t + i * 256];
  __syncthreads();

  // layer 1: 512 -> 128, relu
  {
    const int j = t & 127, half = t >> 7;
    float acc[8];
#pragma unroll
    for (int u = 0; u < 8; ++u) acc[u] = b1[j];
    for (int k = 0; k < 512; ++k) {
      const float w = w1[k * 128 + j];
#pragma unroll
      for (int u = 0; u < 8; ++u) acc[u] = fmaf(xs[half * 8 + u][k], w, acc[u]);
    }
#pragma unroll
    for (int u = 0; u < 8; ++u) h1s[half * 8 + u][j] = fmaxf(acc[u], 0.f);
  }
  __syncthreads();

  // layer 2: 128 -> 64, relu
  {
    const int j = t & 63, qg = t >> 6;
    float acc[4];
#pragma unroll
    for (int u = 0; u < 4; ++u) acc[u] = b2[j];
    for (int k = 0; k < 128; ++k) {
      const float w = w2[k * 64 + j];
#pragma unroll
      for (int u = 0; u < 4; ++u) acc[u] = fmaf(h1s[qg * 4 + u][k], w, acc[u]);
    }
#pragma unroll
    for (int u = 0; u < 4; ++u) h2s[qg * 4 + u][j] = fmaxf(acc[u], 0.f);
  }
  __syncthreads();

  // layer 3: 64 -> 32 + fused row-normalize (shfl reduce over the 32 j-lanes)
  {
    const int j = t & 31, og = t >> 5;
    float acc[2];
#pragma unroll
    for (int u = 0; u < 2; ++u) acc[u] = b3[j];
    for (int k = 0; k < 64; ++k) {
      const float w = w3[k * 32 + j];
#pragma unroll
      for (int u = 0; u < 2; ++u) acc[u] = fmaf(h2s[og * 2 + u][k], w, acc[u]);
    }
#pragma unroll
    for (int u = 0; u < 2; ++u) {
      const float val = acc[u];
      float s2 = val * val;
      s2 += __shfl_xor(s2, 1);
      s2 += __shfl_xor(s2, 2);
      s2 += __shfl_xor(s2, 4);
      s2 += __shfl_xor(s2, 8);
      s2 += __shfl_xor(s2, 16);
      const float inv = 1.0f / (sqrtf(s2) + 1e-12f);
      const size_t off = (size_t)(r0 + og * 2 + u) * D + j;
      latent[off] = val;
      normed[off] = val * inv;
    }
  }
}

// ---------------- graph pool partials: block (bi, bj) covers 64 i-rows x 512 j ----------------
__global__ __launch_bounds__(256) void pool_kernel(const float* __restrict__ normed,
                                                   const float* __restrict__ latent,
                                                   float* __restrict__ pacc,
                                                   float* __restrict__ pdeg) {
  __shared__ float smem[8192 + 256];
  float* nt = smem;
  float* lt = smem + 4096;
  float* degr = smem + 8192;
  const int t = threadIdx.x;
  const int il = t & 63, g = t >> 6;
  const int i0 = blockIdx.x * 64;
  const int j0 = blockIdx.y * 512;

  float ni[32];
  const float* nrow = normed + (size_t)(i0 + il) * D;
#pragma unroll
  for (int c = 0; c < 32; ++c) ni[c] = nrow[c];

  float acc[32];
#pragma unroll
  for (int c = 0; c < 32; ++c) acc[c] = 0.f;
  float deg = 0.f;

  for (int jt = j0; jt < j0 + 512; jt += 128) {
    __syncthreads();
    const float4* ng = (const float4*)(normed + (size_t)jt * D);
    const float4* lg = (const float4*)(latent + (size_t)jt * D);
    float4* ntl = (float4*)nt;
    float4* ltl = (float4*)lt;
#pragma unroll
    for (int i = 0; i < 4; ++i) {
      ntl[t + i * 256] = ng[t + i * 256];
      ltl[t + i * 256] = lg[t + i * 256];
    }
    __syncthreads();
    for (int jj = g; jj < 128; jj += 4) {
      const float* nr = nt + jj * 32;
      float s = 0.f;
#pragma unroll
      for (int c = 0; c < 32; ++c) s = fmaf(ni[c], nr[c], s);
      if (s >= 0.9f) {
        deg += 1.f;
        const float* lrow = lt + jj * 32;
#pragma unroll
        for (int c = 0; c < 32; ++c) acc[c] += lrow[c];
      }
    }
  }
  __syncthreads();
  float* accr = smem;
#pragma unroll
  for (int c = 0; c < 32; ++c) accr[(g * 64 + il) * 32 + c] = acc[c];
  degr[t] = deg;
  __syncthreads();
  for (int e = t; e < 64 * 32; e += 256) {
    const float s = accr[e] + accr[2048 + e] + accr[4096 + e] + accr[6144 + e];
    pacc[((size_t)blockIdx.y * N + i0 + (e >> 5)) * 32 + (e & 31)] = s;
  }
  if (t < 64) {
    pdeg[(size_t)blockIdx.y * N + i0 + t] = degr[t] + degr[64 + t] + degr[128 + t] + degr[192 + t];
  }
}

// ---------------- combine pool partials -> h = latent + (mask@latent)/deg ----------------
__global__ __launch_bounds__(256) void pool_combine(const float* __restrict__ latent,
                                                    const float* __restrict__ pacc,
                                                    const float* __restrict__ pdeg,
                                                    float* __restrict__ h) {
  const int e = blockIdx.x * 256 + threadIdx.x;
  const int i = e >> 5;
  float s = 0.f, dg = 0.f;
#pragma unroll
  for (int gch = 0; gch < JC; ++gch) {
    s += pacc[(size_t)gch * N * 32 + e];
    dg += pdeg[(size_t)gch * N + i];
  }
  h[e] = latent[e] + s / dg;
}

// ---------------- fused QKV projection (q pre-scaled by log2e/sqrt(8)) + k-norm max ----------------
__global__ __launch_bounds__(256) void qkv_kernel(
    const float* __restrict__ h,
    const float* __restrict__ wq, const float* __restrict__ bq,
    const float* __restrict__ wk, const float* __restrict__ bk,
    const float* __restrict__ wv, const float* __restrict__ bv,
    float* __restrict__ q, float* __restrict__ k, float* __restrict__ v,
    int* __restrict__ kmax2i) {
  __shared__ float hs[32][32];
  __shared__ float wsm[3][32][32];
  __shared__ int kred[4];
  const int t = threadIdx.x;
  const int r0 = blockIdx.x * 32;
  if (t < 4) kred[t] = 0;
  ((float4*)&hs[0][0])[t] = ((const float4*)(h + (size_t)r0 * 32))[t];
  ((float4*)&wsm[0][0][0])[t] = ((const float4*)wq)[t];
  ((float4*)&wsm[1][0][0])[t] = ((const float4*)wk)[t];
  ((float4*)&wsm[2][0][0])[t] = ((const float4*)wv)[t];
  __syncthreads();
  const int j = t & 31, og = t >> 5;
  const int head = j >> 3;
  float aq[4], ak[4], av[4];
#pragma unroll
  for (int u = 0; u < 4; ++u) { aq[u] = bq[j]; ak[u] = bk[j]; av[u] = bv[j]; }
  for (int kk = 0; kk < 32; ++kk) {
    const float wqv = wsm[0][kk][j], wkv = wsm[1][kk][j], wvv = wsm[2][kk][j];
#pragma unroll
    for (int u = 0; u < 4; ++u) {
      const float hh = hs[og * 4 + u][kk];
      aq[u] = fmaf(hh, wqv, aq[u]);
      ak[u] = fmaf(hh, wkv, ak[u]);
      av[u] = fmaf(hh, wvv, av[u]);
    }
  }
  const float scale = 1.4426950408889634f * 0.35355339059327373f;  // log2(e)/sqrt(8)
#pragma unroll
  for (int u = 0; u < 4; ++u) {
    const size_t off = (size_t)(r0 + og * 4 + u) * 32 + j;
    q[off] = aq[u] * scale;
    k[off] = ak[u];
    v[off] = av[u];
  }
  // per-(row,head) ||k8||^2 via shfl over the 8 lanes of this head; block-max; global atomicMax
#pragma unroll
  for (int u = 0; u < 4; ++u) {
    float s2 = ak[u] * ak[u];
    s2 += __shfl_xor(s2, 1);
    s2 += __shfl_xor(s2, 2);
    s2 += __shfl_xor(s2, 4);
    if ((j & 7) == 0) atomicMax(&kred[head], __float_as_int(s2));
  }
  __syncthreads();
  if (t < 4) atomicMax(&kmax2i[t], kred[t]);
}

// ---------------- attention partials: block (rowBlk, jChunk); 32 rows x 512 j ----------------
// thread = (rg 0..7)x(head 0..3)x(jg 0..7); 4 q-rows per thread; bound-shifted exp2, no rescale
// NOTE: launch_bounds min-waves relaxed 4 -> 2. Per-thread persistent state is ~72 floats
// (qa/qb/accA/accB/mneg/l); the previous 128-reg cap forced scratch spills inside the hot
// loop (rocprof: 206 MB WRITE + 130 MB FETCH of unexplained HBM traffic per dispatch, i.e.
// spill round-trips thrashing L2). 256-reg cap keeps everything in registers; grid is
// 4 blocks/CU-limited anyway, so occupancy is unchanged or mildly lower but spill-free.
__global__ __launch_bounds__(256, 2) void attn_kernel(const float* __restrict__ q,
                                                      const float* __restrict__ k,
                                                      const float* __restrict__ v,
                                                      const int* __restrict__ kmax2i,
                                                      float* __restrict__ apacc,
                                                      float* __restrict__ apl) {
  __shared__ float4 tiles[2048];  // kls[128*8] | vls[128*8], chunk-XOR swizzled
  __shared__ float lred[4][256];
  float4* kls = tiles;
  float4* vls = tiles + 1024;
  const int t = threadIdx.x;
  const int jg = t & 7, head = (t >> 3) & 3, rg = t >> 5;
  const int r0 = blockIdx.x * 32;
  const int j0 = blockIdx.y * (N / JC);

  const float km2 = __int_as_float(kmax2i[head]);

  float4 qa[4], qb[4], accA[4], accB[4];
  float mneg[4], l[4];
#pragma unroll
  for (int u = 0; u < 4; ++u) {
    const float* qr = q + (size_t)(r0 + rg * 4 + u) * 32 + head * 8;
    qa[u] = ((const float4*)qr)[0];
    qb[u] = ((const float4*)qr)[1];
    const float qn2 = qa[u].x * qa[u].x + qa[u].y * qa[u].y + qa[u].z * qa[u].z + qa[u].w * qa[u].w +
                      qb[u].x * qb[u].x + qb[u].y * qb[u].y + qb[u].z * qb[u].z + qb[u].w * qb[u].w;
    mneg[u] = -sqrtf(qn2 * km2);
    l[u] = 0.f;
    accA[u] = make_float4(0.f, 0.f, 0.f, 0.f);
    accB[u] = make_float4(0.f, 0.f, 0.f, 0.f);
  }

  const int h2 = head * 2;
  const int s0 = h2 ^ jg, s1 = (h2 + 1) ^ jg;
  for (int jt = j0; jt < j0 + (N / JC); jt += 128) {
    __syncthreads();
    const float4* kg = (const float4*)(k + (size_t)jt * 32);
    const float4* vg = (const float4*)(v + (size_t)jt * 32);
#pragma unroll
    for (int i = 0; i < 4; ++i) {
      const int gidx = t + i * 256;
      const int r = gidx >> 3, cc = gidx & 7, slot = cc ^ (r & 7);
      kls[r * 8 + slot] = kg[gidx];
      vls[r * 8 + slot] = vg[gidx];
    }
    __syncthreads();
#pragma unroll
    for (int it = 0; it < 16; ++it) {
      const int jj = it * 8 + jg;
      const float4 ka = kls[jj * 8 + s0];
      const float4 kb = kls[jj * 8 + s1];
      const float4 va = vls[jj * 8 + s0];
      const float4 vb = vls[jj * 8 + s1];
#pragma unroll
      for (int u = 0; u < 4; ++u) {
        float s = fmaf(qa[u].x, ka.x, mneg[u]);
        s = fmaf(qa[u].y, ka.y, s);
        s = fmaf(qa[u].z, ka.z, s);
        s = fmaf(qa[u].w, ka.w, s);
        s = fmaf(qb[u].x, kb.x, s);
        s = fmaf(qb[u].y, kb.y, s);
        s = fmaf(qb[u].z, kb.z, s);
        s = fmaf(qb[u].w, kb.w, s);
        const float p = __builtin_amdgcn_exp2f(s);
        l[u] += p;
        accA[u].x = fmaf(p, va.x, accA[u].x);
        accA[u].y = fmaf(p, va.y, accA[u].y);
        accA[u].z = fmaf(p, va.z, accA[u].z);
        accA[u].w = fmaf(p, va.w, accA[u].w);
        accB[u].x = fmaf(p, vb.x, accB[u].x);
        accB[u].y = fmaf(p, vb.y, accB[u].y);
        accB[u].z = fmaf(p, vb.z, accB[u].z);
        accB[u].w = fmaf(p, vb.w, accB[u].w);
      }
    }
  }
  // block-reduce the 8 jg partials; accr overlays the tiles: [32 vals][256 threads]
  __syncthreads();
  float* accr = (float*)tiles;
#pragma unroll
  for (int u = 0; u < 4; ++u) {
    accr[(u * 8 + 0) * 256 + t] = accA[u].x;
    accr[(u * 8 + 1) * 256 + t] = accA[u].y;
    accr[(u * 8 + 2) * 256 + t] = accA[u].z;
    accr[(u * 8 + 3) * 256 + t] = accA[u].w;
    accr[(u * 8 + 4) * 256 + t] = accB[u].x;
    accr[(u * 8 + 5) * 256 + t] = accB[u].y;
    accr[(u * 8 + 6) * 256 + t] = accB[u].z;
    accr[(u * 8 + 7) * 256 + t] = accB[u].w;
    lred[u][t] = l[u];
  }
  __syncthreads();
  for (int o = t; o < 1024; o += 256) {
    const int rg2 = o >> 7, u2 = (o >> 5) & 3, hh = (o >> 3) & 3, c = o & 7;
    const int sbase = rg2 * 32 + hh * 8;
    float ssum = 0.f;
#pragma unroll
    for (int jj = 0; jj < 8; ++jj) ssum += accr[(u2 * 8 + c) * 256 + sbase + jj];
    apacc[(size_t)blockIdx.y * N * 32 + (size_t)(r0 + rg2 * 4 + u2) * 32 + hh * 8 + c] = ssum;
  }
  if (t < 128) {
    const int rl = t >> 2, hh = t & 3;
    const int rg2 = rl >> 2, u2 = rl & 3;
    float Ls = 0.f;
#pragma unroll
    for (int jj = 0; jj < 8; ++jj) Ls += lred[u2][rg2 * 32 + hh * 8 + jj];
    apl[(size_t)blockIdx.y * N * 4 + (size_t)(r0 + rl) * 4 + hh] = Ls;
  }
}

// ---------------- combine attention partials ----------------
__global__ __launch_bounds__(256) void acombine(const float* __restrict__ apacc,
                                                const float* __restrict__ apl,
                                                float* __restrict__ attno) {
  const int e = blockIdx.x * 256 + threadIdx.x;  // < N*32
  const int row = e >> 5;
  const int hh = (e >> 3) & 3;
  float L = 0.f, S = 0.f;
#pragma unroll
  for (int jc = 0; jc < JC; ++jc) {
    L += apl[(size_t)jc * N * 4 + row * 4 + hh];
    S += apacc[(size_t)jc * N * 32 + e];
  }
  attno[e] = S / L;
}

// ---------------- O-projection + residual + LayerNorm1 ----------------
__global__ __launch_bounds__(256) void oln1_kernel(const float* __restrict__ attno,
                                                   const float* __restrict__ wo,
                                                   const float* __restrict__ bo,
                                                   const float* __restrict__ g,
                                                   const float* __restrict__ b,
                                                   float* __restrict__ h) {
  __shared__ float als[32][32];
  __shared__ float wols[32][32];
  __shared__ float ys[32][33];
  const int t = threadIdx.x;
  const int r0 = blockIdx.x * 32;
  ((float4*)&als[0][0])[t] = ((const float4*)(attno + (size_t)r0 * 32))[t];
  ((float4*)&wols[0][0])[t] = ((const float4*)wo)[t];
  __syncthreads();
  const int j = t & 31, og = t >> 5;
  float acc[4];
#pragma unroll
  for (int u = 0; u < 4; ++u) acc[u] = bo[j];
  for (int kk = 0; kk < 32; ++kk) {
    const float w = wols[kk][j];
#pragma unroll
    for (int u = 0; u < 4; ++u) acc[u] = fmaf(als[og * 4 + u][kk], w, acc[u]);
  }
#pragma unroll
  for (int u = 0; u < 4; ++u) {
    const int r = og * 4 + u;
    ys[r][j] = h[(size_t)(r0 + r) * 32 + j] + acc[u];
  }
  __syncthreads();
  if (t < 32) {
    float mu = 0.f;
#pragma unroll
    for (int c = 0; c < 32; ++c) mu += ys[t][c];
    mu *= (1.f / 32.f);
    float var = 0.f;
#pragma unroll
    for (int c = 0; c < 32; ++c) {
      const float dd = ys[t][c] - mu;
      var = fmaf(dd, dd, var);
    }
    var *= (1.f / 32.f);
    const float rs = rsqrtf(var + 1e-5f);
#pragma unroll
    for (int c = 0; c < 32; ++c)
      h[(size_t)(r0 + t) * 32 + c] = (ys[t][c] - mu) * rs * g[c] + b[c];
  }
}

// ---------------- FFN + residual + LayerNorm2 ----------------
__global__ __launch_bounds__(256) void ffn_kernel(const float* __restrict__ hin,
                                                  const float* __restrict__ w1,
                                                  const float* __restrict__ b1,
                                                  const float* __restrict__ w2,
                                                  const float* __restrict__ b2,
                                                  const float* __restrict__ g,
                                                  const float* __restrict__ bb,
                                                  float* __restrict__ h) {
  __shared__ float hs[32][32];
  __shared__ float w1s[32][64];
  __shared__ float w2s[64][32];
  __shared__ float mids[32][64];
  __shared__ float ys[32][33];
  const int t = threadIdx.x;
  const int r0 = blockIdx.x * 32;
  ((float4*)&hs[0][0])[t] = ((const float4*)(hin + (size_t)r0 * 32))[t];
#pragma unroll
  for (int i = 0; i < 2; ++i) {
    ((float4*)&w1s[0][0])[t + i * 256] = ((const float4*)w1)[t + i * 256];
    ((float4*)&w2s[0][0])[t + i * 256] = ((const float4*)w2)[t + i * 256];
  }
  __syncthreads();
  {
    const int jm = t & 63, gg = t >> 6;
    float acc[8];
#pragma unroll
    for (int u = 0; u < 8; ++u) acc[u] = b1[jm];
    for (int kk = 0; kk < 32; ++kk) {
      const float w = w1s[kk][jm];
#pragma unroll
      for (int u = 0; u < 8; ++u) acc[u] = fmaf(hs[gg * 8 + u][kk], w, acc[u]);
    }
#pragma unroll
    for (int u = 0; u < 8; ++u) mids[gg * 8 + u][jm] = fmaxf(acc[u], 0.f);
  }
  __syncthreads();
  {
    const int j = t & 31, og = t >> 5;
    float acc[4];
#pragma unroll
    for (int u = 0; u < 4; ++u) acc[u] = b2[j];
    for (int kk = 0; kk < 64; ++kk) {
      const float w = w2s[kk][j];
#pragma unroll
      for (int u = 0; u < 4; ++u) acc[u] = fmaf(mids[og * 4 + u][kk], w, acc[u]);
    }
#pragma unroll
    for (int u = 0; u < 4; ++u) {
      const int r = og * 4 + u;
      ys[r][j] = hs[r][j] + acc[u];
    }
  }
  __syncthreads();
  if (t < 32) {
    float mu = 0.f;
#pragma unroll
    for (int c = 0; c < 32; ++c) mu += ys[t][c];
    mu *= (1.f / 32.f);
    float var = 0.f;
#pragma unroll
    for (int c = 0; c < 32; ++c) {
      const float dd = ys[t][c] - mu;
      var = fmaf(dd, dd, var);
    }
    var *= (1.f / 32.f);
    const float rs = rsqrtf(var + 1e-5f);
#pragma unroll
    for (int c = 0; c < 32; ++c)
      h[(size_t)(r0 + t) * 32 + c] = (ys[t][c] - mu) * rs * g[c] + bb[c];
  }
}

// ---------------- head ----------------
__global__ __launch_bounds__(256) void headp_kernel(const float* __restrict__ h,
                                                    float* __restrict__ partial) {
  __shared__ float red[8][32];
  const int t = threadIdx.x;
  const int c = t & 31, rg = t >> 5;
  const int r0 = blockIdx.x * 64;
  float s = 0.f;
#pragma unroll
  for (int u = 0; u < 8; ++u) s += h[(size_t)(r0 + rg * 8 + u) * 32 + c];
  red[rg][c] = s;
  __syncthreads();
  if (t < 32) {
    float ss = 0.f;
#pragma unroll
    for (int u = 0; u < 8; ++u) ss += red[u][t];
    partial[blockIdx.x * 32 + t] = ss;
  }
}

__global__ __launch_bounds__(64) void headf_kernel(const float* __restrict__ partial,
                                                   const float* __restrict__ w1,
                                                   const float* __restrict__ b1,
                                                   const float* __restrict__ w2,
                                                   const float* __restrict__ b2,
                                                   float* __restrict__ out) {
  __shared__ float mls[32];
  __shared__ float tls[16];
  const int t = threadIdx.x;
  if (t < 32) {
    float s = 0.f;
    for (int bb = 0; bb < 64; ++bb) s += partial[bb * 32 + t];
    mls[t] = s * (1.f / 4096.f);
  }
  __syncthreads();
  if (t < 16) {
    float a = b1[t];
#pragma unroll
    for (int c = 0; c < 32; ++c) a = fmaf(mls[c], w1[c * 16 + t], a);
    tls[t] = tanhf(a);
  }
  __syncthreads();
  if (t == 0) {
    float o = b2[0];
#pragma unroll
    for (int jj = 0; jj < 16; ++jj) o = fmaf(tls[jj], w2[jj], o);
    out[0] = o;
  }
}

extern "C" void kernel_launch(void* const* d_in, const int* in_sizes, int n_in,
                              void* d_out, int out_size, void* d_ws, size_t ws_size,
                              hipStream_t stream) {
  const float* x      = (const float*)d_in[0];
  const float* enc_w1 = (const float*)d_in[1];
  const float* enc_b1 = (const float*)d_in[2];
  const float* enc_w2 = (const float*)d_in[3];
  const float* enc_b2 = (const float*)d_in[4];
  const float* enc_w3 = (const float*)d_in[5];
  const float* enc_b3 = (const float*)d_in[6];
  const float* wq     = (const float*)d_in[7];
  const float* bq     = (const float*)d_in[8];
  const float* wk     = (const float*)d_in[9];
  const float* bk     = (const float*)d_in[10];
  const float* wv     = (const float*)d_in[11];
  const float* bv     = (const float*)d_in[12];
  const float* wo     = (const float*)d_in[13];
  const float* bo     = (const float*)d_in[14];
  const float* ln1_g  = (const float*)d_in[15];
  const float* ln1_b  = (const float*)d_in[16];
  const float* ffn_w1 = (const float*)d_in[17];
  const float* ffn_b1 = (const float*)d_in[18];
  const float* ffn_w2 = (const float*)d_in[19];
  const float* ffn_b2 = (const float*)d_in[20];
  const float* ln2_g  = (const float*)d_in[21];
  const float* ln2_b  = (const float*)d_in[22];
  const float* head_w1 = (const float*)d_in[23];
  const float* head_b1 = (const float*)d_in[24];
  const float* head_w2 = (const float*)d_in[25];
  const float* head_b2 = (const float*)d_in[26];

  float* ws      = (float*)d_ws;
  float* latent  = ws;                    // 131072
  float* normed  = ws + 131072;           // 131072
  float* h       = ws + 262144;           // 131072
  float* q       = ws + 393216;           // 131072
  float* k       = ws + 524288;           // 131072
  float* v       = ws + 655360;           // 131072
  float* attno   = ws + 786432;           // 131072
  float* shreg   = ws + 917504;           // shared region: pool partials, then attn partials
  float* p_acc   = shreg;                 // pool: 8*131072
  float* p_deg   = shreg + 1048576;       // pool: 8*4096
  float* a_acc   = shreg;                 // attn: 8*131072
  float* a_l     = shreg + 1048576;       // attn: 8*16384
  int*   kmax2i  = (int*)(ws + 2097152);  // 8 ints (4 per transformer block)
  float* partial = ws + 2097216;          // 2048

  hipMemsetAsync(kmax2i, 0, 8 * sizeof(int), stream);

  enc_kernel<<<256, 256, 0, stream>>>(x, enc_w1, enc_b1, enc_w2, enc_b2, enc_w3, enc_b3,
                                      latent, normed);
  pool_kernel<<<dim3(64, JC), 256, 0, stream>>>(normed, latent, p_acc, p_deg);
  pool_combine<<<512, 256, 0, stream>>>(latent, p_acc, p_deg, h);

  for (int blk = 0; blk < 2; ++blk) {
    qkv_kernel<<<128, 256, 0, stream>>>(h, wq + blk * 1024, bq + blk * 32,
                                        wk + blk * 1024, bk + blk * 32,
                                        wv + blk * 1024, bv + blk * 32, q, k, v,
                                        kmax2i + blk * 4);
    attn_kernel<<<dim3(128, JC), 256, 0, stream>>>(q, k, v, kmax2i + blk * 4, a_acc, a_l);
    acombine<<<512, 256, 0, stream>>>(a_acc, a_l, attno);
    oln1_kernel<<<128, 256, 0, stream>>>(attno, wo + blk * 1024, bo + blk * 32,
                                         ln1_g + blk * 32, ln1_b + blk * 32, h);
    ffn_kernel<<<128, 256, 0, stream>>>(h, ffn_w1 + blk * 2048, ffn_b1 + blk * 64,
                                        ffn_w2 + blk * 2048, ffn_b2 + blk * 32,
                                        ln2_g + blk * 32, ln2_b + blk * 32, h);
  }

  headp_kernel<<<64, 256, 0, stream>>>(h, partial);
  headf_kernel<<<1, 64, 0, stream>>>(partial, head_w1, head_b1, head_w2, head_b2, (float*)d_out);
}